// Round 8
// baseline (19.545 us; speedup 1.0000x reference)
//
#include <hip/hip_runtime.h>
#include <math.h>
#include <float.h>

#define NB 32          // batch
#define NM 32          // max GT per image
#define NA 3           // anchors per scale
#define NCLS 80
#define NCH 85         // 5 + C
#define IOU_THR 0.7f
#define L_COORD 0.75f
#define FEPS 1e-8f

// task layout: noobj blocks per scale (1024-cell chunks, float4 for G26/G52)
#define N0_BLKS (NB * NA * 1)    // G=13: 169 cells, VEC=1, 1 chunk      -> 96
#define N1_BLKS (NB * NA * 1)    // G=26: 676 cells, VEC=4, 1 chunk      -> 96
#define N2_BLKS (NB * NA * 3)    // G=52: 2704 cells, VEC=4, 3 chunks    -> 288
#define OFF1 (N0_BLKS)                              // 96
#define OFF2 (OFF1 + N1_BLKS)                       // 192
#define OFFM (OFF2 + N2_BLKS)                       // 480
#define MATCHED_TASKS (3 * NB * NM / 4)             // 768 (4 waves each)
#define TOTAL_TASKS (OFFM + MATCHED_TASKS)          // 1248

struct Smem {
    float4 sbox[NM];            // GT x1,y1,x2,y2
    float  sarea[NM];           // GT area (w*h)
    int    scode[NM];           // matched-cell code for this scale, or -1
    int    slist[NM];           // compacted IoU-candidate GT indices
    int    clist[NM];           // compacted matched-cell pix codes for this (b,a)
    float  wmin[4], wmax[4];
    int    scnt, ccnt;
    float  wsum[4];
};

__device__ __forceinline__ float sigmoidf_(float x) {
    return 1.0f / (1.0f + expf(-x));
}

// argmax over 9 anchors of min-intersection IoU (first-max tie, like jnp.argmax)
__device__ __forceinline__ int best_prior(const float* __restrict__ anchors,
                                          float w, float h, float area_g) {
    float best = -1.0f;
    int bp = 0;
    #pragma unroll
    for (int k = 0; k < 9; ++k) {
        float aw = anchors[k * 2 + 0];
        float ah = anchors[k * 2 + 1];
        float inter = fminf(w, aw) * fminf(h, ah);
        float uni = area_g + aw * ah - inter;
        float r = inter / (uni + FEPS);
        if (r > best) { best = r; bp = k; }
    }
    return bp;
}

// ---------------------------------------------------------------------------
// noobj body: one block = (b, a, chunk of 256*VEC cells) of scale S.
// Phase 1 loads only tw,th,to (area filter + obj term); phase 2 (tx,ty + IoU)
// runs only when the block-level candidate list is non-empty.
// Filters are exact/conservative (identical semantics to R7's passing form).
// ---------------------------------------------------------------------------
template <int G, int S, int CHUNKS_, int VEC>
__device__ float noobj_body(const float* __restrict__ p,
                            const float* __restrict__ gt_boxes,
                            const float* __restrict__ anchors,
                            int bid, Smem& sm) {
    constexpr int GG = G * G;
    constexpr int CHUNK = 256 * VEC;
    static_assert(VEC == 1 || (GG % 4 == 0), "float4 path needs GG%4==0");

    int chunk = bid % CHUNKS_;
    int a = (bid / CHUNKS_) % NA;
    int b = bid / (CHUNKS_ * NA);
    int tid = threadIdx.x;
    int lane = tid & 63, wid = tid >> 6;

    // GT prep (first 32 threads)
    if (tid < NM) {
        int e = b * NM + tid;
        float cx = gt_boxes[e * 4 + 0];
        float cy = gt_boxes[e * 4 + 1];
        float w  = gt_boxes[e * 4 + 2];
        float h  = gt_boxes[e * 4 + 3];
        float x1 = cx - w * 0.5f, y1 = cy - h * 0.5f;
        float x2 = cx + w * 0.5f, y2 = cy + h * 0.5f;
        sm.sbox[tid] = make_float4(x1, y1, x2, y2);
        sm.sarea[tid] = (x2 - x1) * (y2 - y1);
        int bp = best_prior(anchors, w, h, w * h);
        int code = -1;
        if (bp >= S * NA && bp < S * NA + NA) {
            float gxf = fminf(fmaxf(floorf(cx * (float)G), 0.0f), (float)(G - 1));
            float gyf = fminf(fmaxf(floorf(cy * (float)G), 0.0f), (float)(G - 1));
            code = (bp - S * NA) * GG + (int)gyf * G + (int)gxf;
        }
        sm.scode[tid] = code;
    }

    float aw = anchors[(S * NA + a) * 2 + 0];
    float ah = anchors[(S * NA + a) * 2 + 1];
    int cell0 = chunk * CHUNK + tid * VEC;
    bool live = cell0 < GG;      // VEC=4 paths: GG%4==0 -> all 4 live together
    const float* cb = p + (size_t)(b * (NA * NCH) + a * NCH) * GG + cell0;

    // phase 1: tw, th, to
    float twv[VEC], thv[VEC], tov[VEC], bw[VEC], bh[VEC], areab[VEC];
    float mn = FLT_MAX, mx = 0.0f;
    if (live) {
        if constexpr (VEC == 4) {
            float4 t2 = *reinterpret_cast<const float4*>(cb + 2 * (size_t)GG);
            float4 t3 = *reinterpret_cast<const float4*>(cb + 3 * (size_t)GG);
            float4 t4 = *reinterpret_cast<const float4*>(cb + 4 * (size_t)GG);
            twv[0]=t2.x; twv[1]=t2.y; twv[2]=t2.z; twv[3]=t2.w;
            thv[0]=t3.x; thv[1]=t3.y; thv[2]=t3.z; thv[3]=t3.w;
            tov[0]=t4.x; tov[1]=t4.y; tov[2]=t4.z; tov[3]=t4.w;
        } else {
            twv[0] = cb[2 * (size_t)GG];
            thv[0] = cb[3 * (size_t)GG];
            tov[0] = cb[4 * (size_t)GG];
        }
        #pragma unroll
        for (int v = 0; v < VEC; ++v) {
            bw[v] = aw * expf(twv[v]);
            bh[v] = ah * expf(thv[v]);
            areab[v] = bw[v] * bh[v];
            mn = fminf(mn, areab[v]);
            mx = fmaxf(mx, areab[v]);
        }
    }

    // block min/max of areab
    #pragma unroll
    for (int off = 32; off; off >>= 1) {
        mn = fminf(mn, __shfl_xor(mn, off));
        mx = fmaxf(mx, __shfl_xor(mx, off));
    }
    if (lane == 0) { sm.wmin[wid] = mn; sm.wmax[wid] = mx; }
    __syncthreads();   // (1) GT smem + wave min/max ready

    // wave 0 compacts candidate lists
    if (tid < 64) {
        float bmin = fminf(fminf(sm.wmin[0], sm.wmin[1]), fminf(sm.wmin[2], sm.wmin[3]));
        float bmax = fmaxf(fmaxf(sm.wmax[0], sm.wmax[1]), fmaxf(sm.wmax[2], sm.wmax[3]));
        bool c_win = false, c_code = false;
        int cellcode = 0;
        if (tid < NM) {
            float Am = sm.sarea[tid];
            c_win = (1.02f * bmax > IOU_THR * Am) && (1.02f * Am > IOU_THR * bmin);
            int code = sm.scode[tid];
            c_code = (code >= a * GG) && (code < (a + 1) * GG);   // code==-1 fails
            cellcode = code - a * GG;
        }
        unsigned long long mwin = __ballot(c_win);
        unsigned long long mcode = __ballot(c_code);
        unsigned long long below = (1ull << tid) - 1;
        if (c_win)  sm.slist[__popcll(mwin & below)] = tid;
        if (c_code) sm.clist[__popcll(mcode & below)] = cellcode;
        if (tid == 0) { sm.scnt = (int)__popcll(mwin); sm.ccnt = (int)__popcll(mcode); }
    }
    __syncthreads();   // (2) lists ready

    int sc = sm.scnt, cc = sm.ccnt;
    int posm = 0;

    // matched-cell override (no tx/ty needed)
    for (int j = 0; j < cc; ++j) {
        int code = sm.clist[j];
        #pragma unroll
        for (int v = 0; v < VEC; ++v) posm |= (code == cell0 + v) ? (1 << v) : 0;
    }

    // IoU only when candidates exist (block-uniform branch; skips tx/ty loads)
    if (sc > 0 && live) {
        float tx[VEC], ty[VEC];
        if constexpr (VEC == 4) {
            float4 t0 = *reinterpret_cast<const float4*>(cb);
            float4 t1 = *reinterpret_cast<const float4*>(cb + (size_t)GG);
            tx[0]=t0.x; tx[1]=t0.y; tx[2]=t0.z; tx[3]=t0.w;
            ty[0]=t1.x; ty[1]=t1.y; ty[2]=t1.z; ty[3]=t1.w;
        } else {
            tx[0] = cb[0];
            ty[0] = cb[(size_t)GG];
        }
        float bx1[VEC], by1[VEC], bx2[VEC], by2[VEC];
        #pragma unroll
        for (int v = 0; v < VEC; ++v) {
            int cell = cell0 + v;
            int gy = cell / G, gx = cell - gy * G;
            float bcx = (sigmoidf_(tx[v]) + (float)gx) / (float)G;
            float bcy = (sigmoidf_(ty[v]) + (float)gy) / (float)G;
            bx1[v] = bcx - bw[v] * 0.5f; by1[v] = bcy - bh[v] * 0.5f;
            bx2[v] = bcx + bw[v] * 0.5f; by2[v] = bcy + bh[v] * 0.5f;
        }
        for (int j = 0; j < sc; ++j) {
            int m = sm.slist[j];
            float4 bb = sm.sbox[m];
            float am = sm.sarea[m];
            #pragma unroll
            for (int v = 0; v < VEC; ++v) {
                float ltx = fmaxf(bb.x, bx1[v]), lty = fmaxf(bb.y, by1[v]);
                float rbx = fminf(bb.z, bx2[v]), rby = fminf(bb.w, by2[v]);
                float wx = fmaxf(rbx - ltx, 0.0f), wy = fmaxf(rby - lty, 0.0f);
                float inter = wx * wy;
                float denom = am + areab[v] - inter + FEPS;
                posm |= (inter > IOU_THR * denom) ? (1 << v) : 0;
            }
        }
    }

    float local = 0.0f;
    if (live) {
        #pragma unroll
        for (int v = 0; v < VEC; ++v) {
            if (!((posm >> v) & 1)) {
                float so = sigmoidf_(tov[v]);
                local += so * so;
            }
        }
    }

    // block reduce: wave shuffle -> LDS
    for (int off = 32; off; off >>= 1) local += __shfl_down(local, off);
    if (lane == 0) sm.wsum[wid] = local;
    __syncthreads();
    return sm.wsum[0] + sm.wsum[1] + sm.wsum[2] + sm.wsum[3];
}

// ---------------------------------------------------------------------------
// matched body: one wave per (scale, b, m) entry; 4 waves per task.
// Lane covers channels {lane, lane+64}. Returns block partial. (Unchanged.)
// ---------------------------------------------------------------------------
__device__ float matched_body(const float* __restrict__ p0,
                              const float* __restrict__ p1,
                              const float* __restrict__ p2,
                              const float* __restrict__ gt_boxes,
                              const int* __restrict__ gt_classes,
                              const float* __restrict__ anchors,
                              int mb, Smem& sm) {
    int tid = threadIdx.x;
    int wave = tid >> 6, lane = tid & 63;
    int t = mb * 4 + wave;        // 0 .. 3071
    int s = t >> 10;              // scale: 1024 entries per scale
    int e = t & 1023;             // (b, m) flat
    int b = e >> 5;

    float cx = gt_boxes[e * 4 + 0];
    float cy = gt_boxes[e * 4 + 1];
    float w  = gt_boxes[e * 4 + 2];
    float h  = gt_boxes[e * 4 + 3];
    int bp = best_prior(anchors, w, h, w * h);
    int a = bp - s * NA;

    float term = 0.0f;
    if (a >= 0 && a < NA) {                       // mask_s (wave-uniform)
        const float* p = (s == 0) ? p0 : ((s == 1) ? p1 : p2);
        int G = (s == 0) ? 13 : ((s == 1) ? 26 : 52);
        long nboff = (s == 0) ? 0L : ((s == 1) ? 16224L : 81120L);
        int GG = G * G;

        float gxf = fminf(fmaxf(floorf(cx * (float)G), 0.0f), (float)(G - 1));
        float gyf = fminf(fmaxf(floorf(cy * (float)G), 0.0f), (float)(G - 1));
        int gx = (int)gxf, gy = (int)gyf;
        int box_idx = a * GG + gy * G + gx;
        long gidx = nboff + (long)b * (NA * GG) + box_idx;
        if (gidx != 0) {                          // valid (wave-uniform)
            float dx = cx * (float)G - gxf;
            float dy = cy * (float)G - gyf;
            float wgt = 2.0f - w * h;
            float twt = logf(fmaxf(w, FEPS)) - logf(anchors[bp * 2 + 0]);
            float tht = logf(fmaxf(h, FEPS)) - logf(anchors[bp * 2 + 1]);
            int cls = gt_classes[e];

            size_t cellbase = (size_t)(b * (NA * NCH) + a * NCH) * GG
                              + (size_t)(gy * G + gx);
            for (int ch = lane; ch < NCH; ch += 64) {
                float val = p[cellbase + (size_t)ch * GG];
                if (ch < 2) {
                    float sv = sigmoidf_(val);
                    float d = sv - (ch == 0 ? dx : dy);
                    term += L_COORD * wgt * d * d;
                } else if (ch < 4) {
                    float d = val - (ch == 2 ? twt : tht);
                    term += L_COORD * wgt * d * d;
                } else if (ch == 4) {
                    float sv = sigmoidf_(val);
                    term += (sv - 1.0f) * (sv - 1.0f);
                } else {
                    float sv = sigmoidf_(val);
                    float oh = ((ch - 5) == cls) ? 1.0f : 0.0f;
                    term += (sv - oh) * (sv - oh);
                }
            }
        }
    }

    // 64-lane wave reduce -> LDS -> block partial
    for (int off = 32; off; off >>= 1) term += __shfl_down(term, off);
    if (lane == 0) sm.wsum[wave] = term;
    __syncthreads();
    return sm.wsum[0] + sm.wsum[1] + sm.wsum[2] + sm.wsum[3];
}

__device__ __forceinline__ float do_task(int task,
        const float* __restrict__ p0, const float* __restrict__ p1,
        const float* __restrict__ p2, const float* __restrict__ gt_boxes,
        const int* __restrict__ gt_classes, const float* __restrict__ anchors,
        Smem& sm) {
    if (task < OFF1)      return noobj_body<13, 0, 1, 1>(p0, gt_boxes, anchors, task, sm);
    else if (task < OFF2) return noobj_body<26, 1, 1, 4>(p1, gt_boxes, anchors, task - OFF1, sm);
    else if (task < OFFM) return noobj_body<52, 2, 3, 4>(p2, gt_boxes, anchors, task - OFF2, sm);
    else return matched_body(p0, p1, p2, gt_boxes, gt_classes, anchors, task - OFFM, sm);
}

// ---------------------------------------------------------------------------
// Proven 2-node structure: fused partials + tiny reduce.
// ---------------------------------------------------------------------------
__global__ __launch_bounds__(256)
void yolo_fused(const float* __restrict__ p0, const float* __restrict__ p1,
                const float* __restrict__ p2, const float* __restrict__ gt_boxes,
                const int* __restrict__ gt_classes, const float* __restrict__ anchors,
                float* __restrict__ partials) {
    __shared__ Smem sm;
    float part = do_task(blockIdx.x, p0, p1, p2, gt_boxes, gt_classes, anchors, sm);
    if (threadIdx.x == 0) partials[blockIdx.x] = part;
}

__global__ __launch_bounds__(256)
void yolo_reduce(const float* __restrict__ partials, float* __restrict__ out) {
    int tid = threadIdx.x;
    float s = 0.0f;
    for (int i = tid; i < TOTAL_TASKS; i += 256) s += partials[i];
    for (int off = 32; off; off >>= 1) s += __shfl_down(s, off);
    __shared__ float wsum[4];
    if ((tid & 63) == 0) wsum[tid >> 6] = s;
    __syncthreads();
    if (tid == 0) out[0] = wsum[0] + wsum[1] + wsum[2] + wsum[3];
}

// ---------------------------------------------------------------------------
extern "C" void kernel_launch(void* const* d_in, const int* in_sizes, int n_in,
                              void* d_out, int out_size, void* d_ws, size_t ws_size,
                              hipStream_t stream) {
    const float* p0 = (const float*)d_in[0];
    const float* p1 = (const float*)d_in[1];
    const float* p2 = (const float*)d_in[2];
    const float* gt_boxes = (const float*)d_in[3];
    const int* gt_classes = (const int*)d_in[4];
    const float* anchors = (const float*)d_in[5];
    float* out = (float*)d_out;
    float* partials = (float*)d_ws;

    yolo_fused<<<TOTAL_TASKS, 256, 0, stream>>>(p0, p1, p2, gt_boxes,
                                                gt_classes, anchors, partials);
    yolo_reduce<<<1, 256, 0, stream>>>(partials, out);
}

// Round 9
// 19.004 us; speedup vs baseline: 1.0285x; 1.0285x over previous
//
#include <hip/hip_runtime.h>
#include <math.h>
#include <float.h>

#define NB 32          // batch
#define NM 32          // max GT per image
#define NA 3           // anchors per scale
#define NCLS 80
#define NCH 85         // 5 + C
#define IOU_THR 0.7f
#define L_COORD 0.75f
#define FEPS 1e-8f

// task layout
#define N0_BLKS (NB * NA * 1)    // G=13: 169 cells, VEC=1, 1 chunk   -> 96
#define N1_BLKS (NB * NA * 1)    // G=26: 676 cells, VEC=4, 1 chunk   -> 96
#define N2_BLKS (NB * NA * 3)    // G=52: 2704 cells, VEC=4, 3 chunks -> 288
#define OFF1 (N0_BLKS)                              // 96
#define OFF2 (OFF1 + N1_BLKS)                       // 192
#define OFFM (OFF2 + N2_BLKS)                       // 480
#define MATCHED_BLKS (NB * NM / 4)                  // 1024 entries, 1 wave each -> 256
#define TOTAL_TASKS (OFFM + MATCHED_BLKS)           // 736

struct Smem {
    float4 sbox[NM];            // GT x1,y1,x2,y2
    float  sarea[NM];           // GT area (w*h)
    int    scode[NM];           // matched-cell code for this scale, or -1
    int    slist[NM];           // compacted IoU-candidate GT indices
    int    clist[NM];           // compacted matched-cell pix codes for this (b,a)
    float  wmin[4], wmax[4];
    int    scnt, ccnt;
    float  wsum[4];
};

__device__ __forceinline__ float sigmoidf_(float x) {
    return 1.0f / (1.0f + expf(-x));
}

// argmax over 9 anchors of min-intersection IoU (first-max tie, like jnp.argmax)
// exact fp32 divide (argmax flips vs reference would change the loss O(1))
__device__ __forceinline__ int best_prior(const float* __restrict__ anchors,
                                          float w, float h, float area_g) {
    float best = -1.0f;
    int bp = 0;
    #pragma unroll
    for (int k = 0; k < 9; ++k) {
        float aw = anchors[k * 2 + 0];
        float ah = anchors[k * 2 + 1];
        float inter = fminf(w, aw) * fminf(h, ah);
        float uni = area_g + aw * ah - inter;
        float r = inter / (uni + FEPS);
        if (r > best) { best = r; bp = k; }
    }
    return bp;
}

// ---------------------------------------------------------------------------
// noobj body: one block = (b, a, chunk of 256*VEC cells) of scale S.
// ALL 5 channel loads issue upfront (single memory-latency window, R8 lesson);
// tx/ty sigmoid decode + IoU run only when the candidate list is non-empty.
// Filters are exact/conservative (identical semantics to R7's passing form).
// ---------------------------------------------------------------------------
template <int G, int S, int CHUNKS_, int VEC>
__device__ float noobj_body(const float* __restrict__ p,
                            const float* __restrict__ gt_boxes,
                            const float* __restrict__ anchors,
                            int bid, Smem& sm) {
    constexpr int GG = G * G;
    constexpr int CHUNK = 256 * VEC;
    static_assert(VEC == 1 || (GG % 4 == 0), "float4 path needs GG%4==0");

    int chunk = bid % CHUNKS_;
    int a = (bid / CHUNKS_) % NA;
    int b = bid / (CHUNKS_ * NA);
    int tid = threadIdx.x;
    int lane = tid & 63, wid = tid >> 6;

    float aw = anchors[(S * NA + a) * 2 + 0];
    float ah = anchors[(S * NA + a) * 2 + 1];
    int cell0 = chunk * CHUNK + tid * VEC;
    bool live = cell0 < GG;      // VEC=4 paths: GG%4==0 -> all 4 live together
    const float* cb = p + (size_t)(b * (NA * NCH) + a * NCH) * GG + cell0;

    // ---- issue ALL loads upfront: 5 channels ----
    float txv[VEC], tyv[VEC], twv[VEC], thv[VEC], tov[VEC];
    if (live) {
        if constexpr (VEC == 4) {
            float4 t0 = *reinterpret_cast<const float4*>(cb);
            float4 t1 = *reinterpret_cast<const float4*>(cb + (size_t)GG);
            float4 t2 = *reinterpret_cast<const float4*>(cb + 2 * (size_t)GG);
            float4 t3 = *reinterpret_cast<const float4*>(cb + 3 * (size_t)GG);
            float4 t4 = *reinterpret_cast<const float4*>(cb + 4 * (size_t)GG);
            txv[0]=t0.x; txv[1]=t0.y; txv[2]=t0.z; txv[3]=t0.w;
            tyv[0]=t1.x; tyv[1]=t1.y; tyv[2]=t1.z; tyv[3]=t1.w;
            twv[0]=t2.x; twv[1]=t2.y; twv[2]=t2.z; twv[3]=t2.w;
            thv[0]=t3.x; thv[1]=t3.y; thv[2]=t3.z; thv[3]=t3.w;
            tov[0]=t4.x; tov[1]=t4.y; tov[2]=t4.z; tov[3]=t4.w;
        } else {
            txv[0] = cb[0];
            tyv[0] = cb[(size_t)GG];
            twv[0] = cb[2 * (size_t)GG];
            thv[0] = cb[3 * (size_t)GG];
            tov[0] = cb[4 * (size_t)GG];
        }
    }

    // GT prep (first 32 threads) — overlaps with the cell loads above
    if (tid < NM) {
        int e = b * NM + tid;
        float cx = gt_boxes[e * 4 + 0];
        float cy = gt_boxes[e * 4 + 1];
        float w  = gt_boxes[e * 4 + 2];
        float h  = gt_boxes[e * 4 + 3];
        float x1 = cx - w * 0.5f, y1 = cy - h * 0.5f;
        float x2 = cx + w * 0.5f, y2 = cy + h * 0.5f;
        sm.sbox[tid] = make_float4(x1, y1, x2, y2);
        sm.sarea[tid] = (x2 - x1) * (y2 - y1);
        int bp = best_prior(anchors, w, h, w * h);
        int code = -1;
        if (bp >= S * NA && bp < S * NA + NA) {
            float gxf = fminf(fmaxf(floorf(cx * (float)G), 0.0f), (float)(G - 1));
            float gyf = fminf(fmaxf(floorf(cy * (float)G), 0.0f), (float)(G - 1));
            code = (bp - S * NA) * GG + (int)gyf * G + (int)gxf;
        }
        sm.scode[tid] = code;
    }

    // decode areas; block min/max of areab
    float bw[VEC], bh[VEC], areab[VEC];
    float mn = FLT_MAX, mx = 0.0f;
    if (live) {
        #pragma unroll
        for (int v = 0; v < VEC; ++v) {
            bw[v] = aw * expf(twv[v]);
            bh[v] = ah * expf(thv[v]);
            areab[v] = bw[v] * bh[v];
            mn = fminf(mn, areab[v]);
            mx = fmaxf(mx, areab[v]);
        }
    }
    #pragma unroll
    for (int off = 32; off; off >>= 1) {
        mn = fminf(mn, __shfl_xor(mn, off));
        mx = fmaxf(mx, __shfl_xor(mx, off));
    }
    if (lane == 0) { sm.wmin[wid] = mn; sm.wmax[wid] = mx; }
    __syncthreads();   // (1) GT smem + wave min/max ready

    // wave 0 compacts candidate lists
    if (tid < 64) {
        float bmin = fminf(fminf(sm.wmin[0], sm.wmin[1]), fminf(sm.wmin[2], sm.wmin[3]));
        float bmax = fmaxf(fmaxf(sm.wmax[0], sm.wmax[1]), fmaxf(sm.wmax[2], sm.wmax[3]));
        bool c_win = false, c_code = false;
        int cellcode = 0;
        if (tid < NM) {
            float Am = sm.sarea[tid];
            c_win = (1.02f * bmax > IOU_THR * Am) && (1.02f * Am > IOU_THR * bmin);
            int code = sm.scode[tid];
            c_code = (code >= a * GG) && (code < (a + 1) * GG);   // code==-1 fails
            cellcode = code - a * GG;
        }
        unsigned long long mwin = __ballot(c_win);
        unsigned long long mcode = __ballot(c_code);
        unsigned long long below = (1ull << tid) - 1;
        if (c_win)  sm.slist[__popcll(mwin & below)] = tid;
        if (c_code) sm.clist[__popcll(mcode & below)] = cellcode;
        if (tid == 0) { sm.scnt = (int)__popcll(mwin); sm.ccnt = (int)__popcll(mcode); }
    }
    __syncthreads();   // (2) lists ready

    int sc = sm.scnt, cc = sm.ccnt;
    int posm = 0;

    // matched-cell override
    for (int j = 0; j < cc; ++j) {
        int code = sm.clist[j];
        #pragma unroll
        for (int v = 0; v < VEC; ++v) posm |= (code == cell0 + v) ? (1 << v) : 0;
    }

    // IoU only when candidates exist (block-uniform; loads already done,
    // this only skips the sigmoid decode + loop VALU)
    if (sc > 0 && live) {
        float bx1[VEC], by1[VEC], bx2[VEC], by2[VEC];
        #pragma unroll
        for (int v = 0; v < VEC; ++v) {
            int cell = cell0 + v;
            int gy = cell / G, gx = cell - gy * G;
            float bcx = (sigmoidf_(txv[v]) + (float)gx) / (float)G;
            float bcy = (sigmoidf_(tyv[v]) + (float)gy) / (float)G;
            bx1[v] = bcx - bw[v] * 0.5f; by1[v] = bcy - bh[v] * 0.5f;
            bx2[v] = bcx + bw[v] * 0.5f; by2[v] = bcy + bh[v] * 0.5f;
        }
        for (int j = 0; j < sc; ++j) {
            int m = sm.slist[j];
            float4 bb = sm.sbox[m];
            float am = sm.sarea[m];
            #pragma unroll
            for (int v = 0; v < VEC; ++v) {
                float ltx = fmaxf(bb.x, bx1[v]), lty = fmaxf(bb.y, by1[v]);
                float rbx = fminf(bb.z, bx2[v]), rby = fminf(bb.w, by2[v]);
                float wx = fmaxf(rbx - ltx, 0.0f), wy = fmaxf(rby - lty, 0.0f);
                float inter = wx * wy;
                float denom = am + areab[v] - inter + FEPS;
                posm |= (inter > IOU_THR * denom) ? (1 << v) : 0;
            }
        }
    }

    float local = 0.0f;
    if (live) {
        #pragma unroll
        for (int v = 0; v < VEC; ++v) {
            if (!((posm >> v) & 1)) {
                float so = sigmoidf_(tov[v]);
                local += so * so;
            }
        }
    }

    // block reduce: wave shuffle -> LDS
    for (int off = 32; off; off >>= 1) local += __shfl_down(local, off);
    if (lane == 0) sm.wsum[wid] = local;
    __syncthreads();
    return sm.wsum[0] + sm.wsum[1] + sm.wsum[2] + sm.wsum[3];
}

// ---------------------------------------------------------------------------
// matched body, deduplicated: one wave per GT entry (b,m); each GT matches
// exactly one scale s = bp/3 (mask_s union over the 3 reference passes).
// 4 waves per block -> 256 blocks. Lane covers channels {lane, lane+64}.
// ---------------------------------------------------------------------------
__device__ float matched_body(const float* __restrict__ p0,
                              const float* __restrict__ p1,
                              const float* __restrict__ p2,
                              const float* __restrict__ gt_boxes,
                              const int* __restrict__ gt_classes,
                              const float* __restrict__ anchors,
                              int mb, Smem& sm) {
    int tid = threadIdx.x;
    int wave = tid >> 6, lane = tid & 63;
    int e = mb * 4 + wave;        // 0 .. 1023 : one GT entry per wave
    int b = e >> 5;

    float cx = gt_boxes[e * 4 + 0];
    float cy = gt_boxes[e * 4 + 1];
    float w  = gt_boxes[e * 4 + 2];
    float h  = gt_boxes[e * 4 + 3];
    int bp = best_prior(anchors, w, h, w * h);
    int s = bp / 3;               // this GT's (only) scale
    int a = bp - s * 3;

    const float* p = (s == 0) ? p0 : ((s == 1) ? p1 : p2);
    int G = (s == 0) ? 13 : ((s == 1) ? 26 : 52);
    long nboff = (s == 0) ? 0L : ((s == 1) ? 16224L : 81120L);
    int GG = G * G;

    float gxf = fminf(fmaxf(floorf(cx * (float)G), 0.0f), (float)(G - 1));
    float gyf = fminf(fmaxf(floorf(cy * (float)G), 0.0f), (float)(G - 1));
    int gx = (int)gxf, gy = (int)gyf;
    int box_idx = a * GG + gy * G + gx;
    long gidx = nboff + (long)b * (NA * GG) + box_idx;

    float term = 0.0f;
    if (gidx != 0) {              // valid = mask_s & (gidx != 0), wave-uniform
        float dx = cx * (float)G - gxf;
        float dy = cy * (float)G - gyf;
        float wgt = 2.0f - w * h;
        float twt = logf(fmaxf(w, FEPS)) - logf(anchors[bp * 2 + 0]);
        float tht = logf(fmaxf(h, FEPS)) - logf(anchors[bp * 2 + 1]);
        int cls = gt_classes[e];

        size_t cellbase = (size_t)(b * (NA * NCH) + a * NCH) * GG
                          + (size_t)(gy * G + gx);
        for (int ch = lane; ch < NCH; ch += 64) {
            float val = p[cellbase + (size_t)ch * GG];
            if (ch < 2) {
                float sv = sigmoidf_(val);
                float d = sv - (ch == 0 ? dx : dy);
                term += L_COORD * wgt * d * d;
            } else if (ch < 4) {
                float d = val - (ch == 2 ? twt : tht);
                term += L_COORD * wgt * d * d;
            } else if (ch == 4) {
                float sv = sigmoidf_(val);
                term += (sv - 1.0f) * (sv - 1.0f);
            } else {
                float sv = sigmoidf_(val);
                float oh = ((ch - 5) == cls) ? 1.0f : 0.0f;
                term += (sv - oh) * (sv - oh);
            }
        }
    }

    // 64-lane wave reduce -> LDS -> block partial
    for (int off = 32; off; off >>= 1) term += __shfl_down(term, off);
    if (lane == 0) sm.wsum[wave] = term;
    __syncthreads();
    return sm.wsum[0] + sm.wsum[1] + sm.wsum[2] + sm.wsum[3];
}

__device__ __forceinline__ float do_task(int task,
        const float* __restrict__ p0, const float* __restrict__ p1,
        const float* __restrict__ p2, const float* __restrict__ gt_boxes,
        const int* __restrict__ gt_classes, const float* __restrict__ anchors,
        Smem& sm) {
    if (task < OFF1)      return noobj_body<13, 0, 1, 1>(p0, gt_boxes, anchors, task, sm);
    else if (task < OFF2) return noobj_body<26, 1, 1, 4>(p1, gt_boxes, anchors, task - OFF1, sm);
    else if (task < OFFM) return noobj_body<52, 2, 3, 4>(p2, gt_boxes, anchors, task - OFF2, sm);
    else return matched_body(p0, p1, p2, gt_boxes, gt_classes, anchors, task - OFFM, sm);
}

// ---------------------------------------------------------------------------
// Proven 2-node structure: fused partials + tiny reduce.
// ---------------------------------------------------------------------------
__global__ __launch_bounds__(256)
void yolo_fused(const float* __restrict__ p0, const float* __restrict__ p1,
                const float* __restrict__ p2, const float* __restrict__ gt_boxes,
                const int* __restrict__ gt_classes, const float* __restrict__ anchors,
                float* __restrict__ partials) {
    __shared__ Smem sm;
    float part = do_task(blockIdx.x, p0, p1, p2, gt_boxes, gt_classes, anchors, sm);
    if (threadIdx.x == 0) partials[blockIdx.x] = part;
}

__global__ __launch_bounds__(256)
void yolo_reduce(const float* __restrict__ partials, float* __restrict__ out) {
    int tid = threadIdx.x;
    float s = 0.0f;
    for (int i = tid; i < TOTAL_TASKS; i += 256) s += partials[i];
    for (int off = 32; off; off >>= 1) s += __shfl_down(s, off);
    __shared__ float wsum[4];
    if ((tid & 63) == 0) wsum[tid >> 6] = s;
    __syncthreads();
    if (tid == 0) out[0] = wsum[0] + wsum[1] + wsum[2] + wsum[3];
}

// ---------------------------------------------------------------------------
extern "C" void kernel_launch(void* const* d_in, const int* in_sizes, int n_in,
                              void* d_out, int out_size, void* d_ws, size_t ws_size,
                              hipStream_t stream) {
    const float* p0 = (const float*)d_in[0];
    const float* p1 = (const float*)d_in[1];
    const float* p2 = (const float*)d_in[2];
    const float* gt_boxes = (const float*)d_in[3];
    const int* gt_classes = (const int*)d_in[4];
    const float* anchors = (const float*)d_in[5];
    float* out = (float*)d_out;
    float* partials = (float*)d_ws;

    yolo_fused<<<TOTAL_TASKS, 256, 0, stream>>>(p0, p1, p2, gt_boxes,
                                                gt_classes, anchors, partials);
    yolo_reduce<<<1, 256, 0, stream>>>(partials, out);
}

// Round 10
// 16.319 us; speedup vs baseline: 1.1977x; 1.1645x over previous
//
#include <hip/hip_runtime.h>
#include <math.h>
#include <float.h>

#define NB 32          // batch
#define NM 32          // max GT per image
#define NA 3           // anchors per scale
#define NCLS 80
#define NCH 85         // 5 + C
#define IOU_THR 0.7f
#define L_COORD 0.75f
#define FEPS 1e-8f

// task layout (R7 noobj structure: 256 cells/block, high block count for TLP)
#define NOOBJ0_TASKS (NB * NA * 1)    // G=13: 169 -> 1 chunk of 256
#define NOOBJ1_TASKS (NB * NA * 3)    // G=26: 676 -> 3 chunks
#define NOOBJ2_TASKS (NB * NA * 11)   // G=52: 2704 -> 11 chunks
#define OFF1 (NOOBJ0_TASKS)                        // 96
#define OFF2 (OFF1 + NOOBJ1_TASKS)                 // 384
#define OFFM (OFF2 + NOOBJ2_TASKS)                 // 1440
#define MATCHED_BLKS (NB * NM / 4)                 // 1024 GT entries, 1 wave each -> 256
#define TOTAL_TASKS (OFFM + MATCHED_BLKS)          // 1696

struct Smem {
    float4 sbox[NM];            // GT x1,y1,x2,y2
    float  sarea[NM];           // GT area (w*h)
    int    scode[NM];           // matched-cell code for this scale, or -1
    int    slist[NM];           // compacted IoU-candidate GT indices
    int    clist[NM];           // compacted matched-cell pix codes for this (b,a)
    float  wmin[4], wmax[4];
    int    scnt, ccnt;
    float  wsum[4];
};

__device__ __forceinline__ float sigmoidf_(float x) {
    return 1.0f / (1.0f + expf(-x));
}

// argmax over 9 anchors of min-intersection IoU (first-max tie, like jnp.argmax)
__device__ __forceinline__ int best_prior(const float* __restrict__ anchors,
                                          float w, float h, float area_g) {
    float best = -1.0f;
    int bp = 0;
    #pragma unroll
    for (int k = 0; k < 9; ++k) {
        float aw = anchors[k * 2 + 0];
        float ah = anchors[k * 2 + 1];
        float inter = fminf(w, aw) * fminf(h, ah);
        float uni = area_g + aw * ah - inter;
        float r = inter / (uni + FEPS);
        if (r > best) { best = r; bp = k; }
    }
    return bp;
}

// ---------------------------------------------------------------------------
// noobj body (R7-exact): one block = (b, a, 256-cell chunk) of scale S.
// All 5 channel loads issue upfront; exact-conservative area filter + compacted
// candidate lists; IoU only over candidates.
// ---------------------------------------------------------------------------
template <int G, int S>
__device__ float noobj_body(const float* __restrict__ p,
                            const float* __restrict__ gt_boxes,
                            const float* __restrict__ anchors,
                            int bid, Smem& sm) {
    constexpr int GG = G * G;
    constexpr int CHUNKS = (GG + 255) / 256;

    int chunk = bid % CHUNKS;
    int a = (bid / CHUNKS) % NA;
    int b = bid / (CHUNKS * NA);
    int tid = threadIdx.x;
    int lane = tid & 63, wid = tid >> 6;

    // GT prep (first 32 threads)
    if (tid < NM) {
        int e = b * NM + tid;
        float cx = gt_boxes[e * 4 + 0];
        float cy = gt_boxes[e * 4 + 1];
        float w  = gt_boxes[e * 4 + 2];
        float h  = gt_boxes[e * 4 + 3];
        float x1 = cx - w * 0.5f, y1 = cy - h * 0.5f;
        float x2 = cx + w * 0.5f, y2 = cy + h * 0.5f;
        sm.sbox[tid] = make_float4(x1, y1, x2, y2);
        sm.sarea[tid] = (x2 - x1) * (y2 - y1);
        int bp = best_prior(anchors, w, h, w * h);
        int code = -1;
        if (bp >= S * NA && bp < S * NA + NA) {
            float gxf = fminf(fmaxf(floorf(cx * (float)G), 0.0f), (float)(G - 1));
            float gyf = fminf(fmaxf(floorf(cy * (float)G), 0.0f), (float)(G - 1));
            code = (bp - S * NA) * GG + (int)gyf * G + (int)gxf;
        }
        sm.scode[tid] = code;
    }

    // cell decode (all 5 channels upfront: one latency window)
    float aw = anchors[(S * NA + a) * 2 + 0];
    float ah = anchors[(S * NA + a) * 2 + 1];
    int pix = chunk * 256 + tid;
    bool live = pix < GG;
    float bx1 = 0.f, by1 = 0.f, bx2 = 0.f, by2 = 0.f, areab = 0.f, to = 0.f;
    if (live) {
        int gy = pix / G, gx = pix % G;
        const float* base = p + (size_t)(b * (NA * NCH) + a * NCH) * GG + pix;
        float tx = base[0];
        float ty = base[(size_t)GG];
        float tw = base[2 * (size_t)GG];
        float th = base[3 * (size_t)GG];
        to = base[4 * (size_t)GG];

        float bcx = (sigmoidf_(tx) + (float)gx) / (float)G;
        float bcy = (sigmoidf_(ty) + (float)gy) / (float)G;
        float bw = aw * expf(tw);
        float bh = ah * expf(th);
        bx1 = bcx - bw * 0.5f; by1 = bcy - bh * 0.5f;
        bx2 = bcx + bw * 0.5f; by2 = bcy + bh * 0.5f;
        areab = (bx2 - bx1) * (by2 - by1);
    }

    // block min/max of areab (valid cells only)
    float mn = live ? areab : FLT_MAX;
    float mx = live ? areab : 0.0f;
    #pragma unroll
    for (int off = 32; off; off >>= 1) {
        mn = fminf(mn, __shfl_xor(mn, off));
        mx = fmaxf(mx, __shfl_xor(mx, off));
    }
    if (lane == 0) { sm.wmin[wid] = mn; sm.wmax[wid] = mx; }
    __syncthreads();   // (1) GT smem + wave min/max ready

    // wave 0 compacts candidate lists
    if (tid < 64) {
        float bmin = fminf(fminf(sm.wmin[0], sm.wmin[1]), fminf(sm.wmin[2], sm.wmin[3]));
        float bmax = fmaxf(fmaxf(sm.wmax[0], sm.wmax[1]), fmaxf(sm.wmax[2], sm.wmax[3]));
        bool c_win = false, c_code = false;
        int cellcode = 0;
        if (tid < NM) {
            float Am = sm.sarea[tid];
            // conservative area window: IoU>0.7 impossible outside it
            c_win = (1.02f * bmax > IOU_THR * Am) && (1.02f * Am > IOU_THR * bmin);
            int code = sm.scode[tid];
            c_code = (code >= a * GG) && (code < (a + 1) * GG);   // code==-1 fails
            cellcode = code - a * GG;
        }
        unsigned long long mwin = __ballot(c_win);
        unsigned long long mcode = __ballot(c_code);
        unsigned long long below = (1ull << tid) - 1;
        if (c_win)  sm.slist[__popcll(mwin & below)] = tid;
        if (c_code) sm.clist[__popcll(mcode & below)] = cellcode;
        if (tid == 0) { sm.scnt = (int)__popcll(mwin); sm.ccnt = (int)__popcll(mcode); }
    }
    __syncthreads();   // (2) lists ready

    int pos = 0;
    int sc = sm.scnt, cc = sm.ccnt;
    for (int j = 0; j < cc; ++j)
        pos |= (sm.clist[j] == pix);          // matched-cell override
    for (int j = 0; j < sc; ++j) {
        int m = sm.slist[j];
        float4 bb = sm.sbox[m];
        float ltx = fmaxf(bb.x, bx1), lty = fmaxf(bb.y, by1);
        float rbx = fminf(bb.z, bx2), rby = fminf(bb.w, by2);
        float wx = fmaxf(rbx - ltx, 0.0f), wy = fmaxf(rby - lty, 0.0f);
        float inter = wx * wy;
        float denom = sm.sarea[m] + areab - inter + FEPS;
        pos |= (inter > IOU_THR * denom);     // identical arithmetic to R3/R7
    }

    float local = 0.0f;
    if (live && !pos) {
        float so = sigmoidf_(to);
        local = so * so;
    }

    // block reduce: wave shuffle -> LDS
    for (int off = 32; off; off >>= 1) local += __shfl_down(local, off);
    if (lane == 0) sm.wsum[wid] = local;
    __syncthreads();
    return sm.wsum[0] + sm.wsum[1] + sm.wsum[2] + sm.wsum[3];
}

// ---------------------------------------------------------------------------
// matched body, deduplicated (R9-validated): one wave per GT entry (b,m);
// each GT matches exactly one scale s = bp/3. 4 waves/block -> 256 blocks.
// Lane covers channels {lane, lane+64}.
// ---------------------------------------------------------------------------
__device__ float matched_body(const float* __restrict__ p0,
                              const float* __restrict__ p1,
                              const float* __restrict__ p2,
                              const float* __restrict__ gt_boxes,
                              const int* __restrict__ gt_classes,
                              const float* __restrict__ anchors,
                              int mb, Smem& sm) {
    int tid = threadIdx.x;
    int wave = tid >> 6, lane = tid & 63;
    int e = mb * 4 + wave;        // 0 .. 1023 : one GT entry per wave
    int b = e >> 5;

    float cx = gt_boxes[e * 4 + 0];
    float cy = gt_boxes[e * 4 + 1];
    float w  = gt_boxes[e * 4 + 2];
    float h  = gt_boxes[e * 4 + 3];
    int bp = best_prior(anchors, w, h, w * h);
    int s = bp / 3;               // this GT's (only) scale
    int a = bp - s * 3;

    const float* p = (s == 0) ? p0 : ((s == 1) ? p1 : p2);
    int G = (s == 0) ? 13 : ((s == 1) ? 26 : 52);
    long nboff = (s == 0) ? 0L : ((s == 1) ? 16224L : 81120L);
    int GG = G * G;

    float gxf = fminf(fmaxf(floorf(cx * (float)G), 0.0f), (float)(G - 1));
    float gyf = fminf(fmaxf(floorf(cy * (float)G), 0.0f), (float)(G - 1));
    int gx = (int)gxf, gy = (int)gyf;
    int box_idx = a * GG + gy * G + gx;
    long gidx = nboff + (long)b * (NA * GG) + box_idx;

    float term = 0.0f;
    if (gidx != 0) {              // valid = mask_s & (gidx != 0), wave-uniform
        float dx = cx * (float)G - gxf;
        float dy = cy * (float)G - gyf;
        float wgt = 2.0f - w * h;
        float twt = logf(fmaxf(w, FEPS)) - logf(anchors[bp * 2 + 0]);
        float tht = logf(fmaxf(h, FEPS)) - logf(anchors[bp * 2 + 1]);
        int cls = gt_classes[e];

        size_t cellbase = (size_t)(b * (NA * NCH) + a * NCH) * GG
                          + (size_t)(gy * G + gx);
        for (int ch = lane; ch < NCH; ch += 64) {
            float val = p[cellbase + (size_t)ch * GG];
            if (ch < 2) {
                float sv = sigmoidf_(val);
                float d = sv - (ch == 0 ? dx : dy);
                term += L_COORD * wgt * d * d;
            } else if (ch < 4) {
                float d = val - (ch == 2 ? twt : tht);
                term += L_COORD * wgt * d * d;
            } else if (ch == 4) {
                float sv = sigmoidf_(val);
                term += (sv - 1.0f) * (sv - 1.0f);
            } else {
                float sv = sigmoidf_(val);
                float oh = ((ch - 5) == cls) ? 1.0f : 0.0f;
                term += (sv - oh) * (sv - oh);
            }
        }
    }

    // 64-lane wave reduce -> LDS -> block partial
    for (int off = 32; off; off >>= 1) term += __shfl_down(term, off);
    if (lane == 0) sm.wsum[wave] = term;
    __syncthreads();
    return sm.wsum[0] + sm.wsum[1] + sm.wsum[2] + sm.wsum[3];
}

__device__ __forceinline__ float do_task(int task,
        const float* __restrict__ p0, const float* __restrict__ p1,
        const float* __restrict__ p2, const float* __restrict__ gt_boxes,
        const int* __restrict__ gt_classes, const float* __restrict__ anchors,
        Smem& sm) {
    if (task < OFF1)      return noobj_body<13, 0>(p0, gt_boxes, anchors, task, sm);
    else if (task < OFF2) return noobj_body<26, 1>(p1, gt_boxes, anchors, task - OFF1, sm);
    else if (task < OFFM) return noobj_body<52, 2>(p2, gt_boxes, anchors, task - OFF2, sm);
    else return matched_body(p0, p1, p2, gt_boxes, gt_classes, anchors, task - OFFM, sm);
}

// ---------------------------------------------------------------------------
// Proven 2-node structure: fused partials + tiny reduce.
// ---------------------------------------------------------------------------
__global__ __launch_bounds__(256)
void yolo_fused(const float* __restrict__ p0, const float* __restrict__ p1,
                const float* __restrict__ p2, const float* __restrict__ gt_boxes,
                const int* __restrict__ gt_classes, const float* __restrict__ anchors,
                float* __restrict__ partials) {
    __shared__ Smem sm;
    float part = do_task(blockIdx.x, p0, p1, p2, gt_boxes, gt_classes, anchors, sm);
    if (threadIdx.x == 0) partials[blockIdx.x] = part;
}

__global__ __launch_bounds__(256)
void yolo_reduce(const float* __restrict__ partials, float* __restrict__ out) {
    int tid = threadIdx.x;
    float s = 0.0f;
    for (int i = tid; i < TOTAL_TASKS; i += 256) s += partials[i];
    for (int off = 32; off; off >>= 1) s += __shfl_down(s, off);
    __shared__ float wsum[4];
    if ((tid & 63) == 0) wsum[tid >> 6] = s;
    __syncthreads();
    if (tid == 0) out[0] = wsum[0] + wsum[1] + wsum[2] + wsum[3];
}

// ---------------------------------------------------------------------------
extern "C" void kernel_launch(void* const* d_in, const int* in_sizes, int n_in,
                              void* d_out, int out_size, void* d_ws, size_t ws_size,
                              hipStream_t stream) {
    const float* p0 = (const float*)d_in[0];
    const float* p1 = (const float*)d_in[1];
    const float* p2 = (const float*)d_in[2];
    const float* gt_boxes = (const float*)d_in[3];
    const int* gt_classes = (const int*)d_in[4];
    const float* anchors = (const float*)d_in[5];
    float* out = (float*)d_out;
    float* partials = (float*)d_ws;

    yolo_fused<<<TOTAL_TASKS, 256, 0, stream>>>(p0, p1, p2, gt_boxes,
                                                gt_classes, anchors, partials);
    yolo_reduce<<<1, 256, 0, stream>>>(partials, out);
}